// Round 5
// baseline (387.276 us; speedup 1.0000x reference)
//
#include <hip/hip_runtime.h>
#include <hip/hip_bf16.h>
#include <math.h>

#define D_MODEL 1024
#define D_HIDDEN 4096
#define N_EXP 8
#define N_TOK 4096

typedef __attribute__((ext_vector_type(8))) __bf16 bf16x8_t;
typedef __attribute__((ext_vector_type(4))) float f32x4_t;

// ---- workspace layout (bytes) ----
#define WS_BUCKET_OFF 256
#define WS_XB_OFF     ((size_t)1 << 18)
#define WS_H_OFF      (((size_t)1 << 18) + ((size_t)8 << 20))
#define WS_W1B_OFF    (((size_t)1 << 18) + ((size_t)40 << 20))
#define WS_W2B_OFF    (((size_t)1 << 18) + ((size_t)104 << 20))
#define WS_NEED       (((size_t)1 << 18) + ((size_t)168 << 20))

__device__ __forceinline__ void gload16(const void* g, void* l) {
    __builtin_amdgcn_global_load_lds(
        (__attribute__((address_space(1))) void*)(g),
        (__attribute__((address_space(3))) void*)(l),
        16, 0, 0);
}

__global__ __launch_bounds__(64) void init_counts(int* counts) {
    if (threadIdx.x < N_EXP) counts[threadIdx.x] = 0;
}

// Router: one wave per token. fp64 logit accumulation (argmax robustness);
// also emits x as bf16.
__global__ __launch_bounds__(256) void router_kernel(
    const float* __restrict__ x, const float* __restrict__ Wg,
    const float* __restrict__ bg, int* __restrict__ counts,
    int* __restrict__ bucket, __hip_bfloat16* __restrict__ xb)
{
    const int wid  = threadIdx.x >> 6;
    const int lane = threadIdx.x & 63;
    const int t    = blockIdx.x * 4 + wid;
    const float* xr = x + (size_t)t * D_MODEL;

    double acc[N_EXP];
#pragma unroll
    for (int e = 0; e < N_EXP; ++e) acc[e] = 0.0;

#pragma unroll
    for (int j = 0; j < D_MODEL / 64; ++j) {
        const int d = j * 64 + lane;
        const float xv = xr[d];
        xb[(size_t)t * D_MODEL + d] = __float2bfloat16(xv);
        const float4* wr = (const float4*)(Wg + (size_t)d * N_EXP);
        const float4 w0 = wr[0], w1 = wr[1];
        const double xd = (double)xv;
        acc[0] += xd * (double)w0.x; acc[1] += xd * (double)w0.y;
        acc[2] += xd * (double)w0.z; acc[3] += xd * (double)w0.w;
        acc[4] += xd * (double)w1.x; acc[5] += xd * (double)w1.y;
        acc[6] += xd * (double)w1.z; acc[7] += xd * (double)w1.w;
    }
#pragma unroll
    for (int e = 0; e < N_EXP; ++e) {
        double v = acc[e];
#pragma unroll
        for (int off = 32; off >= 1; off >>= 1) v += __shfl_xor(v, off, 64);
        acc[e] = v + (double)bg[e];
    }
    if (lane == 0) {
        int best = 0; double bv = acc[0];
#pragma unroll
        for (int e = 1; e < N_EXP; ++e)
            if (acc[e] > bv) { bv = acc[e]; best = e; }
        const int pos = atomicAdd(&counts[best], 1);
        bucket[best * N_TOK + pos] = t;
    }
}

// W fp32 [e][k][n] -> Wb bf16 [e][n][k] via LDS-tiled 64x64 transpose.
// v2: float4 loads (4/thread). Thread: n-quad q=tid&15 (4 cols), k-quad kb=tid>>4
// (4 consecutive rows). LDS row stride 136B (pad kills pow2 bank stride).
template<int KT, int NT>
__global__ __launch_bounds__(256) void convert_w(
    const float* __restrict__ W, __hip_bfloat16* __restrict__ Wb)
{
    const int e  = blockIdx.z;
    const int k0 = blockIdx.y * 64;
    const int n0 = blockIdx.x * 64;
    const int tid = threadIdx.x;

    __shared__ __hip_bfloat16 Lt[64 * 68];

    const int q  = tid & 15;
    const int kb = tid >> 4;
    const float* src = W + (size_t)e * KT * NT + (size_t)(k0 + kb * 4) * NT + n0 + q * 4;
    float4 v0 = *(const float4*)(src);
    float4 v1 = *(const float4*)(src + (size_t)NT);
    float4 v2 = *(const float4*)(src + (size_t)2 * NT);
    float4 v3 = *(const float4*)(src + (size_t)3 * NT);
#pragma unroll
    for (int i = 0; i < 4; ++i) {
        union { __hip_bfloat16 hh[4]; unsigned long long u; } pk;
        pk.hh[0] = __float2bfloat16(((const float*)&v0)[i]);
        pk.hh[1] = __float2bfloat16(((const float*)&v1)[i]);
        pk.hh[2] = __float2bfloat16(((const float*)&v2)[i]);
        pk.hh[3] = __float2bfloat16(((const float*)&v3)[i]);
        *(unsigned long long*)((char*)Lt + (size_t)(q * 4 + i) * 136 + kb * 8) = pk.u;
    }
    __syncthreads();

    const int w    = tid >> 6;
    const int lane = tid & 63;
    const int nr   = w * 16 + (lane >> 2);
    const int half = lane & 3;
    const char* rp = (const char*)Lt + (size_t)nr * 136 + half * 32;
    const uint2 a0 = *(const uint2*)(rp);
    const uint2 a1 = *(const uint2*)(rp + 8);
    const uint2 b0 = *(const uint2*)(rp + 16);
    const uint2 b1 = *(const uint2*)(rp + 24);
    __hip_bfloat16* op = Wb + (size_t)e * NT * KT + (size_t)(n0 + nr) * KT + k0 + half * 16;
    *(uint4*)op       = make_uint4(a0.x, a0.y, a1.x, a1.y);
    *(uint4*)(op + 8) = make_uint4(b0.x, b0.y, b1.x, b1.y);
}

// ===================== bf16-W grouped GEMM, 2-phase pipeline ==================
// Tile 128 x BN x 64, 4 waves (wave tile 64 x BN/2), double-buffered LDS,
// next-tile global_load_lds issued BEFORE current-tile compute; ONE barrier
// per K-step (its vmcnt(0) drain lands after the MFMA phase).
// Flat 1D grid, XCD-bijective swizzle; decode m-fastest within an n-panel so
// each XCD's L2 holds one W panel + the expert's A rows.
template<int K_TOT, int N_TOT, int BN, int MINW, bool IS_FFN1>
__global__ __launch_bounds__(256, MINW) void ffn_gemm_bf16(
    const __hip_bfloat16* __restrict__ A,
    const __hip_bfloat16* __restrict__ Wb,
    const float* __restrict__ bias,
    const int* __restrict__ counts,
    const int* __restrict__ bucket,
    __hip_bfloat16* __restrict__ hout,
    float* __restrict__ yout)
{
    constexpr int NG  = BN / 32;           // n-fragments per wave
    constexpr int NBI = BN / 32;           // B gload16 instrs per wave
    constexpr int NB  = N_TOT / BN;        // n-blocks
    constexpr int MB  = N_TOK / 128;       // m-blocks (32)
    constexpr int NWG = NB * MB * N_EXP;   // flat grid, % 8 == 0
    constexpr int ASZ = 128 * 64 * 2;      // bytes per A buffer
    constexpr int BSZ = BN * 64 * 2;
    constexpr int NT  = K_TOT / 64;

    // ---- XCD swizzle + decode ----
    const int orig = blockIdx.x;
    const int wg   = (orig & 7) * (NWG >> 3) + (orig >> 3);
    const int e    = wg / (NB * MB);
    const int rem  = wg % (NB * MB);
    const int n0   = (rem / MB) * BN;
    const int m0   = (rem % MB) * 128;

    const int cnt = counts[e];
    if (m0 >= cnt) return;
    const int tid  = threadIdx.x;
    const int lane = tid & 63;
    const int wid  = tid >> 6;
    const int wm   = wid >> 1, wn = wid & 1;

    __shared__ __hip_bfloat16 As[2 * 128 * 64];
    __shared__ __hip_bfloat16 Bs[2 * BN * 64];
    __shared__ int s_tok[128];

    if (tid < 128) {
        int idx = m0 + tid;
        if (idx >= cnt) idx = cnt - 1;
        s_tok[tid] = bucket[e * N_TOK + idx];
    }
    __syncthreads();

    const __hip_bfloat16* gA[4]; char* lA[4];
#pragma unroll
    for (int i = 0; i < 4; ++i) {
        const int r = wid * 32 + i * 8 + (lane >> 3);
        gA[i] = A + (size_t)s_tok[r] * K_TOT + (((lane & 7) ^ (r & 7)) << 3);
        lA[i] = (char*)As + (size_t)(wid * 32 + i * 8) * 128;
    }
    const __hip_bfloat16* gB[NBI]; char* lB[NBI];
    const __hip_bfloat16* wbase = Wb + (size_t)e * N_TOT * K_TOT;
#pragma unroll
    for (int i = 0; i < NBI; ++i) {
        const int r = wid * (BN / 4) + i * 8 + (lane >> 3);
        gB[i] = wbase + (size_t)(n0 + r) * K_TOT + (((lane & 7) ^ (r & 7)) << 3);
        lB[i] = (char*)Bs + (size_t)(wid * (BN / 4) + i * 8) * 128;
    }

    f32x4_t acc[4][NG];
#pragma unroll
    for (int f = 0; f < 4; ++f)
#pragma unroll
        for (int g = 0; g < NG; ++g) acc[f][g] = (f32x4_t){0.f, 0.f, 0.f, 0.f};

    // ---- prologue: stage tile 0 into buf 0 ----
#pragma unroll
    for (int i = 0; i < 4; ++i) gload16(gA[i], lA[i]);
#pragma unroll
    for (int i = 0; i < NBI; ++i) gload16(gB[i], lB[i]);
    __syncthreads();

    int cur = 0;
    for (int t = 0; t < NT; ++t) {
        // ---- issue next tile's loads into the other buffer (overlaps compute) ----
        if (t + 1 < NT) {
            const int k1 = (t + 1) * 64;
            const int nb = (cur ^ 1);
#pragma unroll
            for (int i = 0; i < 4; ++i) gload16(gA[i] + k1, lA[i] + nb * ASZ);
#pragma unroll
            for (int i = 0; i < NBI; ++i) gload16(gB[i] + k1, lB[i] + nb * BSZ);
        }
        // ---- compute current buffer ----
        const char* asb = (const char*)As + cur * ASZ;
        const char* bsb = (const char*)Bs + cur * BSZ;
#pragma unroll
        for (int kk = 0; kk < 2; ++kk) {
            uint4 af[4], bf[NG];
            const int ko = kk * 4 + (lane >> 4);
#pragma unroll
            for (int f = 0; f < 4; ++f) {
                const int r = wm * 64 + f * 16 + (lane & 15);
                af[f] = *(const uint4*)(asb + r * 128 + ((ko ^ (r & 7)) << 4));
            }
#pragma unroll
            for (int g = 0; g < NG; ++g) {
                const int n = wn * (BN / 2) + g * 16 + (lane & 15);
                bf[g] = *(const uint4*)(bsb + n * 128 + ((ko ^ (n & 7)) << 4));
            }
#pragma unroll
            for (int f = 0; f < 4; ++f)
#pragma unroll
                for (int g = 0; g < NG; ++g)
                    acc[f][g] = __builtin_amdgcn_mfma_f32_16x16x32_bf16(
                        __builtin_bit_cast(bf16x8_t, af[f]),
                        __builtin_bit_cast(bf16x8_t, bf[g]),
                        acc[f][g], 0, 0, 0);
        }
        __syncthreads();   // drains vmcnt(0): next tile landed; all waves done with cur
        cur ^= 1;
    }

    // ---- epilogue: C/D layout col=lane&15, row=(lane>>4)*4+j ----
#pragma unroll
    for (int f = 0; f < 4; ++f) {
#pragma unroll
        for (int j = 0; j < 4; ++j) {
            const int rl = wm * 64 + f * 16 + (lane >> 4) * 4 + j;
            const bool ok = (m0 + rl) < cnt;
            const int tok = s_tok[rl];
#pragma unroll
            for (int g = 0; g < NG; ++g) {
                const int col = n0 + wn * (BN / 2) + g * 16 + (lane & 15);
                float v = acc[f][g][j] + bias[e * N_TOT + col];
                if (IS_FFN1) {
                    v = 0.5f * v * (1.0f + erff(v * 0.70710678118654752f));
                    if (ok) hout[(size_t)tok * N_TOT + col] = __float2bfloat16(v);
                } else {
                    if (ok) yout[(size_t)tok * N_TOT + col] = v;
                }
            }
        }
    }
}

// ===================== fp32-W fallback (used if ws too small) =================
template<int K_TOT, int N_TOT, bool IS_FFN1>
__global__ __launch_bounds__(256, 2) void ffn_gemm_f32(
    const __hip_bfloat16* __restrict__ A,
    const float* __restrict__ W,
    const float* __restrict__ bias,
    const int* __restrict__ counts,
    const int* __restrict__ bucket,
    __hip_bfloat16* __restrict__ hout,
    float* __restrict__ yout)
{
    const int e   = blockIdx.z;
    const int cnt = counts[e];
    const int m0  = blockIdx.y * 128;
    if (m0 >= cnt) return;
    const int n0   = blockIdx.x * 128;
    const int tid  = threadIdx.x;
    const int lane = tid & 63;
    const int wid  = tid >> 6;
    const int wm   = wid >> 1, wn = wid & 1;

    __shared__ __hip_bfloat16 As[128 * 64];
    __shared__ __hip_bfloat16 Bs[128 * 64];
    __shared__ int s_tok[128];

    if (tid < 128) {
        int idx = m0 + tid;
        if (idx >= cnt) idx = cnt - 1;
        s_tok[tid] = bucket[e * N_TOK + idx];
    }
    __syncthreads();

    const __hip_bfloat16* gA[4]; char* lA[4];
#pragma unroll
    for (int i = 0; i < 4; ++i) {
        const int r = wid * 32 + i * 8 + (lane >> 3);
        gA[i] = A + (size_t)s_tok[r] * K_TOT + (((lane & 7) ^ (r & 7)) << 3);
        lA[i] = (char*)As + (size_t)(wid * 32 + i * 8) * 128;
    }
    const int ko_t = lane & 7;
    const int nq   = wid * 8 + (lane >> 3);
    const float* wb = W + (size_t)e * K_TOT * N_TOT + (size_t)(ko_t * 8) * N_TOT + n0 + nq * 4;

    f32x4_t acc[4][4];
#pragma unroll
    for (int f = 0; f < 4; ++f)
#pragma unroll
        for (int g = 0; g < 4; ++g) acc[f][g] = (f32x4_t){0.f, 0.f, 0.f, 0.f};

    for (int k0 = 0; k0 < K_TOT; k0 += 64) {
#pragma unroll
        for (int i = 0; i < 4; ++i) gload16(gA[i] + k0, lA[i]);
        const float* wk = wb + (size_t)k0 * N_TOT;
        float4 v[8];
#pragma unroll
        for (int j = 0; j < 8; ++j) v[j] = *(const float4*)(wk + (size_t)j * N_TOT);
#pragma unroll
        for (int i = 0; i < 4; ++i) {
            const int n = nq * 4 + i;
            union { __hip_bfloat16 hh[8]; uint4 u; } pk;
#pragma unroll
            for (int j = 0; j < 8; ++j) pk.hh[j] = __float2bfloat16(((const float*)&v[j])[i]);
            *(uint4*)((char*)Bs + n * 128 + ((ko_t ^ (n & 7)) << 4)) = pk.u;
        }
        __syncthreads();

#pragma unroll
        for (int kk = 0; kk < 2; ++kk) {
            uint4 af[4], bf[4];
            const int ko = kk * 4 + (lane >> 4);
#pragma unroll
            for (int f = 0; f < 4; ++f) {
                const int r = wm * 64 + f * 16 + (lane & 15);
                af[f] = *(const uint4*)((const char*)As + r * 128 + ((ko ^ (r & 7)) << 4));
            }
#pragma unroll
            for (int g = 0; g < 4; ++g) {
                const int n = wn * 64 + g * 16 + (lane & 15);
                bf[g] = *(const uint4*)((const char*)Bs + n * 128 + ((ko ^ (n & 7)) << 4));
            }
#pragma unroll
            for (int f = 0; f < 4; ++f)
#pragma unroll
                for (int g = 0; g < 4; ++g)
                    acc[f][g] = __builtin_amdgcn_mfma_f32_16x16x32_bf16(
                        __builtin_bit_cast(bf16x8_t, af[f]),
                        __builtin_bit_cast(bf16x8_t, bf[g]),
                        acc[f][g], 0, 0, 0);
        }
        __syncthreads();
    }

#pragma unroll
    for (int f = 0; f < 4; ++f) {
#pragma unroll
        for (int j = 0; j < 4; ++j) {
            const int rl = wm * 64 + f * 16 + (lane >> 4) * 4 + j;
            const bool ok = (m0 + rl) < cnt;
            const int tok = s_tok[rl];
#pragma unroll
            for (int g = 0; g < 4; ++g) {
                const int col = n0 + wn * 64 + g * 16 + (lane & 15);
                float v = acc[f][g][j] + bias[e * N_TOT + col];
                if (IS_FFN1) {
                    v = 0.5f * v * (1.0f + erff(v * 0.70710678118654752f));
                    if (ok) hout[(size_t)tok * N_TOT + col] = __float2bfloat16(v);
                } else {
                    if (ok) yout[(size_t)tok * N_TOT + col] = v;
                }
            }
        }
    }
}

extern "C" void kernel_launch(void* const* d_in, const int* in_sizes, int n_in,
                              void* d_out, int out_size, void* d_ws, size_t ws_size,
                              hipStream_t stream) {
    const float* x  = (const float*)d_in[0];
    const float* Wg = (const float*)d_in[1];
    const float* bg = (const float*)d_in[2];
    const float* W1 = (const float*)d_in[3];
    const float* b1 = (const float*)d_in[4];
    const float* W2 = (const float*)d_in[5];
    const float* b2 = (const float*)d_in[6];
    float* out = (float*)d_out;

    char* ws = (char*)d_ws;
    int* counts = (int*)(ws);
    int* bucket = (int*)(ws + WS_BUCKET_OFF);
    __hip_bfloat16* xb  = (__hip_bfloat16*)(ws + WS_XB_OFF);
    __hip_bfloat16* h   = (__hip_bfloat16*)(ws + WS_H_OFF);
    __hip_bfloat16* w1b = (__hip_bfloat16*)(ws + WS_W1B_OFF);
    __hip_bfloat16* w2b = (__hip_bfloat16*)(ws + WS_W2B_OFF);

    init_counts<<<dim3(1), dim3(64), 0, stream>>>(counts);
    router_kernel<<<dim3(N_TOK / 4), dim3(256), 0, stream>>>(x, Wg, bg, counts, bucket, xb);

    if (ws_size >= WS_NEED) {
        convert_w<D_MODEL, D_HIDDEN><<<dim3(D_HIDDEN / 64, D_MODEL / 64, N_EXP), dim3(256), 0, stream>>>(W1, w1b);
        convert_w<D_HIDDEN, D_MODEL><<<dim3(D_MODEL / 64, D_HIDDEN / 64, N_EXP), dim3(256), 0, stream>>>(W2, w2b);
        // FFN1: N=4096, K=1024, BN=128, 2 blocks/CU
        ffn_gemm_bf16<D_MODEL, D_HIDDEN, 128, 2, true>
            <<<dim3((D_HIDDEN / 128) * (N_TOK / 128) * N_EXP), dim3(256), 0, stream>>>(
                xb, w1b, b1, counts, bucket, h, nullptr);
        // FFN2: N=1024, K=4096, BN=64, 3 blocks/CU
        ffn_gemm_bf16<D_HIDDEN, D_MODEL, 64, 3, false>
            <<<dim3((D_MODEL / 64) * (N_TOK / 128) * N_EXP), dim3(256), 0, stream>>>(
                h, w2b, b2, counts, bucket, nullptr, out);
    } else {
        ffn_gemm_f32<D_MODEL, D_HIDDEN, true>
            <<<dim3(D_HIDDEN / 128, N_TOK / 128, N_EXP), dim3(256), 0, stream>>>(
                xb, W1, b1, counts, bucket, h, nullptr);
        ffn_gemm_f32<D_HIDDEN, D_MODEL, false>
            <<<dim3(D_MODEL / 128, N_TOK / 128, N_EXP), dim3(256), 0, stream>>>(
                h, W2, b2, counts, bucket, nullptr, out);
    }
}

// Round 6
// 380.907 us; speedup vs baseline: 1.0167x; 1.0167x over previous
//
#include <hip/hip_runtime.h>
#include <hip/hip_bf16.h>
#include <math.h>

#define D_MODEL 1024
#define D_HIDDEN 4096
#define N_EXP 8
#define N_TOK 4096

typedef __attribute__((ext_vector_type(8))) __bf16 bf16x8_t;
typedef __attribute__((ext_vector_type(4))) float f32x4_t;

// ---- workspace layout (bytes) ----
#define WS_BUCKET_OFF 256
#define WS_XB_OFF     ((size_t)1 << 18)
#define WS_H_OFF      (((size_t)1 << 18) + ((size_t)8 << 20))
#define WS_W1B_OFF    (((size_t)1 << 18) + ((size_t)40 << 20))
#define WS_W2B_OFF    (((size_t)1 << 18) + ((size_t)104 << 20))
#define WS_NEED       (((size_t)1 << 18) + ((size_t)168 << 20))

__device__ __forceinline__ void gload16(const void* g, void* l) {
    __builtin_amdgcn_global_load_lds(
        (__attribute__((address_space(1))) void*)(g),
        (__attribute__((address_space(3))) void*)(l),
        16, 0, 0);
}

template<int N> __device__ __forceinline__ void waitcnt_vm() {
    if constexpr (N >= 8)      asm volatile("s_waitcnt vmcnt(8)" ::: "memory");
    else if constexpr (N == 6) asm volatile("s_waitcnt vmcnt(6)" ::: "memory");
    else if constexpr (N == 4) asm volatile("s_waitcnt vmcnt(4)" ::: "memory");
    else                       asm volatile("s_waitcnt vmcnt(0)" ::: "memory");
}

__global__ __launch_bounds__(64) void init_counts(int* counts) {
    if (threadIdx.x < N_EXP) counts[threadIdx.x] = 0;
}

// Router: one wave per token. fp64 logit accumulation (argmax robustness);
// also emits x as bf16.
__global__ __launch_bounds__(256) void router_kernel(
    const float* __restrict__ x, const float* __restrict__ Wg,
    const float* __restrict__ bg, int* __restrict__ counts,
    int* __restrict__ bucket, __hip_bfloat16* __restrict__ xb)
{
    const int wid  = threadIdx.x >> 6;
    const int lane = threadIdx.x & 63;
    const int t    = blockIdx.x * 4 + wid;
    const float* xr = x + (size_t)t * D_MODEL;

    double acc[N_EXP];
#pragma unroll
    for (int e = 0; e < N_EXP; ++e) acc[e] = 0.0;

#pragma unroll
    for (int j = 0; j < D_MODEL / 64; ++j) {
        const int d = j * 64 + lane;
        const float xv = xr[d];
        xb[(size_t)t * D_MODEL + d] = __float2bfloat16(xv);
        const float4* wr = (const float4*)(Wg + (size_t)d * N_EXP);
        const float4 w0 = wr[0], w1 = wr[1];
        const double xd = (double)xv;
        acc[0] += xd * (double)w0.x; acc[1] += xd * (double)w0.y;
        acc[2] += xd * (double)w0.z; acc[3] += xd * (double)w0.w;
        acc[4] += xd * (double)w1.x; acc[5] += xd * (double)w1.y;
        acc[6] += xd * (double)w1.z; acc[7] += xd * (double)w1.w;
    }
#pragma unroll
    for (int e = 0; e < N_EXP; ++e) {
        double v = acc[e];
#pragma unroll
        for (int off = 32; off >= 1; off >>= 1) v += __shfl_xor(v, off, 64);
        acc[e] = v + (double)bg[e];
    }
    if (lane == 0) {
        int best = 0; double bv = acc[0];
#pragma unroll
        for (int e = 1; e < N_EXP; ++e)
            if (acc[e] > bv) { bv = acc[e]; best = e; }
        const int pos = atomicAdd(&counts[best], 1);
        bucket[best * N_TOK + pos] = t;
    }
}

// W fp32 [e][k][n] -> Wb bf16 [e][n][k] via LDS-tiled 64x64 transpose.
template<int KT, int NT>
__global__ __launch_bounds__(256) void convert_w(
    const float* __restrict__ W, __hip_bfloat16* __restrict__ Wb)
{
    const int e  = blockIdx.z;
    const int k0 = blockIdx.y * 64;
    const int n0 = blockIdx.x * 64;
    const int tid = threadIdx.x;

    __shared__ __hip_bfloat16 Lt[64 * 68];

    const int q  = tid & 15;
    const int kb = tid >> 4;
    const float* src = W + (size_t)e * KT * NT + (size_t)(k0 + kb * 4) * NT + n0 + q * 4;
    float4 v0 = *(const float4*)(src);
    float4 v1 = *(const float4*)(src + (size_t)NT);
    float4 v2 = *(const float4*)(src + (size_t)2 * NT);
    float4 v3 = *(const float4*)(src + (size_t)3 * NT);
#pragma unroll
    for (int i = 0; i < 4; ++i) {
        union { __hip_bfloat16 hh[4]; unsigned long long u; } pk;
        pk.hh[0] = __float2bfloat16(((const float*)&v0)[i]);
        pk.hh[1] = __float2bfloat16(((const float*)&v1)[i]);
        pk.hh[2] = __float2bfloat16(((const float*)&v2)[i]);
        pk.hh[3] = __float2bfloat16(((const float*)&v3)[i]);
        *(unsigned long long*)((char*)Lt + (size_t)(q * 4 + i) * 136 + kb * 8) = pk.u;
    }
    __syncthreads();

    const int w    = tid >> 6;
    const int lane = tid & 63;
    const int nr   = w * 16 + (lane >> 2);
    const int half = lane & 3;
    const char* rp = (const char*)Lt + (size_t)nr * 136 + half * 32;
    const uint2 a0 = *(const uint2*)(rp);
    const uint2 a1 = *(const uint2*)(rp + 8);
    const uint2 b0 = *(const uint2*)(rp + 16);
    const uint2 b1 = *(const uint2*)(rp + 24);
    __hip_bfloat16* op = Wb + (size_t)e * NT * KT + (size_t)(n0 + nr) * KT + k0 + half * 16;
    *(uint4*)op       = make_uint4(a0.x, a0.y, a1.x, a1.y);
    *(uint4*)(op + 8) = make_uint4(b0.x, b0.y, b1.x, b1.y);
}

// ============ bf16-W grouped GEMM, counted-vmcnt 2-phase pipeline =============
// Tile 128 x BN x 64, 4 waves (wave tile 64 x BN/2), double-buffered LDS.
// Per K-step: issue next tile's global_load_lds -> s_waitcnt vmcnt(L) (waits
// ONLY for the previous stage; just-issued L loads stay in flight across the
// barrier) -> raw s_barrier (no implicit drain) -> MFMA -> barrier.
// Flat 1D grid, XCD-bijective swizzle, e-major decode: each XCD owns one
// expert (A bucket + W panels L2-resident; R5 measured FETCH 222->42 MB).
template<int K_TOT, int N_TOT, int BN, bool IS_FFN1>
__global__ __launch_bounds__(256) void ffn_gemm_bf16(
    const __hip_bfloat16* __restrict__ A,
    const __hip_bfloat16* __restrict__ Wb,
    const float* __restrict__ bias,
    const int* __restrict__ counts,
    const int* __restrict__ bucket,
    __hip_bfloat16* __restrict__ hout,
    float* __restrict__ yout)
{
    constexpr int NG  = BN / 32;           // n-fragments per wave
    constexpr int NBI = BN / 32;           // B gload16 instrs per wave
    constexpr int NB  = N_TOT / BN;        // n-blocks
    constexpr int MB  = N_TOK / 128;       // m-blocks (32)
    constexpr int NWG = NB * MB * N_EXP;   // flat grid, % 8 == 0
    constexpr int ASZ = 128 * 64 * 2;      // bytes per A buffer
    constexpr int BSZ = BN * 64 * 2;
    constexpr int NT  = K_TOT / 64;
    constexpr int L   = 4 + NBI;           // loads per stage (per wave)

    // ---- XCD swizzle + decode ----
    const int orig = blockIdx.x;
    const int wg   = (orig & 7) * (NWG >> 3) + (orig >> 3);
    const int e    = wg / (NB * MB);
    const int rem  = wg % (NB * MB);
    const int n0   = (rem / MB) * BN;
    const int m0   = (rem % MB) * 128;

    const int cnt = counts[e];
    if (m0 >= cnt) return;
    const int tid  = threadIdx.x;
    const int lane = tid & 63;
    const int wid  = tid >> 6;
    const int wm   = wid >> 1, wn = wid & 1;

    __shared__ __hip_bfloat16 As[2 * 128 * 64];
    __shared__ __hip_bfloat16 Bs[2 * BN * 64];
    __shared__ int s_tok[128];

    if (tid < 128) {
        int idx = m0 + tid;
        if (idx >= cnt) idx = cnt - 1;
        s_tok[tid] = bucket[e * N_TOK + idx];
    }
    __syncthreads();

    const __hip_bfloat16* gA[4]; char* lA[4];
#pragma unroll
    for (int i = 0; i < 4; ++i) {
        const int r = wid * 32 + i * 8 + (lane >> 3);
        gA[i] = A + (size_t)s_tok[r] * K_TOT + (((lane & 7) ^ (r & 7)) << 3);
        lA[i] = (char*)As + (size_t)(wid * 32 + i * 8) * 128;
    }
    const __hip_bfloat16* gB[NBI]; char* lB[NBI];
    const __hip_bfloat16* wbase = Wb + (size_t)e * N_TOT * K_TOT;
#pragma unroll
    for (int i = 0; i < NBI; ++i) {
        const int r = wid * (BN / 4) + i * 8 + (lane >> 3);
        gB[i] = wbase + (size_t)(n0 + r) * K_TOT + (((lane & 7) ^ (r & 7)) << 3);
        lB[i] = (char*)Bs + (size_t)(wid * (BN / 4) + i * 8) * 128;
    }

    f32x4_t acc[4][NG];
#pragma unroll
    for (int f = 0; f < 4; ++f)
#pragma unroll
        for (int g = 0; g < NG; ++g) acc[f][g] = (f32x4_t){0.f, 0.f, 0.f, 0.f};

    // ---- prologue: stage tile 0 into buf 0, full drain once ----
#pragma unroll
    for (int i = 0; i < 4; ++i) gload16(gA[i], lA[i]);
#pragma unroll
    for (int i = 0; i < NBI; ++i) gload16(gB[i], lB[i]);
    waitcnt_vm<0>();
    __builtin_amdgcn_s_barrier();

    for (int t = 0; t < NT; ++t) {
        const int c = t & 1;
        // ---- issue next tile into the other buffer (stays in flight) ----
        if (t + 1 < NT) {
            const int k1 = (t + 1) * 64;
#pragma unroll
            for (int i = 0; i < 4; ++i) gload16(gA[i] + k1, lA[i] + (c ^ 1) * ASZ);
#pragma unroll
            for (int i = 0; i < NBI; ++i) gload16(gB[i] + k1, lB[i] + (c ^ 1) * BSZ);
            waitcnt_vm<L>();             // previous stage done; new L in flight
        } else {
            waitcnt_vm<0>();
        }
        __builtin_amdgcn_s_barrier();    // raw: no vmcnt(0) drain
        __builtin_amdgcn_sched_barrier(0);

        // ---- compute current buffer ----
        const char* asb = (const char*)As + c * ASZ;
        const char* bsb = (const char*)Bs + c * BSZ;
#pragma unroll
        for (int kk = 0; kk < 2; ++kk) {
            uint4 af[4], bf[NG];
            const int ko = kk * 4 + (lane >> 4);
#pragma unroll
            for (int f = 0; f < 4; ++f) {
                const int r = wm * 64 + f * 16 + (lane & 15);
                af[f] = *(const uint4*)(asb + r * 128 + ((ko ^ (r & 7)) << 4));
            }
#pragma unroll
            for (int g = 0; g < NG; ++g) {
                const int n = wn * (BN / 2) + g * 16 + (lane & 15);
                bf[g] = *(const uint4*)(bsb + n * 128 + ((ko ^ (n & 7)) << 4));
            }
#pragma unroll
            for (int f = 0; f < 4; ++f)
#pragma unroll
                for (int g = 0; g < NG; ++g)
                    acc[f][g] = __builtin_amdgcn_mfma_f32_16x16x32_bf16(
                        __builtin_bit_cast(bf16x8_t, af[f]),
                        __builtin_bit_cast(bf16x8_t, bf[g]),
                        acc[f][g], 0, 0, 0);
        }
        __builtin_amdgcn_s_barrier();    // all waves done reading buf c
    }

    // ---- epilogue: C/D layout col=lane&15, row=(lane>>4)*4+j ----
#pragma unroll
    for (int f = 0; f < 4; ++f) {
#pragma unroll
        for (int j = 0; j < 4; ++j) {
            const int rl = wm * 64 + f * 16 + (lane >> 4) * 4 + j;
            const bool ok = (m0 + rl) < cnt;
            const int tok = s_tok[rl];
#pragma unroll
            for (int g = 0; g < NG; ++g) {
                const int col = n0 + wn * (BN / 2) + g * 16 + (lane & 15);
                float v = acc[f][g][j] + bias[e * N_TOT + col];
                if (IS_FFN1) {
                    v = 0.5f * v * (1.0f + erff(v * 0.70710678118654752f));
                    if (ok) hout[(size_t)tok * N_TOT + col] = __float2bfloat16(v);
                } else {
                    if (ok) yout[(size_t)tok * N_TOT + col] = v;
                }
            }
        }
    }
}

// ===================== fp32-W fallback (used if ws too small) =================
template<int K_TOT, int N_TOT, bool IS_FFN1>
__global__ __launch_bounds__(256, 2) void ffn_gemm_f32(
    const __hip_bfloat16* __restrict__ A,
    const float* __restrict__ W,
    const float* __restrict__ bias,
    const int* __restrict__ counts,
    const int* __restrict__ bucket,
    __hip_bfloat16* __restrict__ hout,
    float* __restrict__ yout)
{
    const int e   = blockIdx.z;
    const int cnt = counts[e];
    const int m0  = blockIdx.y * 128;
    if (m0 >= cnt) return;
    const int n0   = blockIdx.x * 128;
    const int tid  = threadIdx.x;
    const int lane = tid & 63;
    const int wid  = tid >> 6;
    const int wm   = wid >> 1, wn = wid & 1;

    __shared__ __hip_bfloat16 As[128 * 64];
    __shared__ __hip_bfloat16 Bs[128 * 64];
    __shared__ int s_tok[128];

    if (tid < 128) {
        int idx = m0 + tid;
        if (idx >= cnt) idx = cnt - 1;
        s_tok[tid] = bucket[e * N_TOK + idx];
    }
    __syncthreads();

    const __hip_bfloat16* gA[4]; char* lA[4];
#pragma unroll
    for (int i = 0; i < 4; ++i) {
        const int r = wid * 32 + i * 8 + (lane >> 3);
        gA[i] = A + (size_t)s_tok[r] * K_TOT + (((lane & 7) ^ (r & 7)) << 3);
        lA[i] = (char*)As + (size_t)(wid * 32 + i * 8) * 128;
    }
    const int ko_t = lane & 7;
    const int nq   = wid * 8 + (lane >> 3);
    const float* wb = W + (size_t)e * K_TOT * N_TOT + (size_t)(ko_t * 8) * N_TOT + n0 + nq * 4;

    f32x4_t acc[4][4];
#pragma unroll
    for (int f = 0; f < 4; ++f)
#pragma unroll
        for (int g = 0; g < 4; ++g) acc[f][g] = (f32x4_t){0.f, 0.f, 0.f, 0.f};

    for (int k0 = 0; k0 < K_TOT; k0 += 64) {
#pragma unroll
        for (int i = 0; i < 4; ++i) gload16(gA[i] + k0, lA[i]);
        const float* wk = wb + (size_t)k0 * N_TOT;
        float4 v[8];
#pragma unroll
        for (int j = 0; j < 8; ++j) v[j] = *(const float4*)(wk + (size_t)j * N_TOT);
#pragma unroll
        for (int i = 0; i < 4; ++i) {
            const int n = nq * 4 + i;
            union { __hip_bfloat16 hh[8]; uint4 u; } pk;
#pragma unroll
            for (int j = 0; j < 8; ++j) pk.hh[j] = __float2bfloat16(((const float*)&v[j])[i]);
            *(uint4*)((char*)Bs + n * 128 + ((ko_t ^ (n & 7)) << 4)) = pk.u;
        }
        __syncthreads();

#pragma unroll
        for (int kk = 0; kk < 2; ++kk) {
            uint4 af[4], bf[4];
            const int ko = kk * 4 + (lane >> 4);
#pragma unroll
            for (int f = 0; f < 4; ++f) {
                const int r = wm * 64 + f * 16 + (lane & 15);
                af[f] = *(const uint4*)((const char*)As + r * 128 + ((ko ^ (r & 7)) << 4));
            }
#pragma unroll
            for (int g = 0; g < 4; ++g) {
                const int n = wn * 64 + g * 16 + (lane & 15);
                bf[g] = *(const uint4*)((const char*)Bs + n * 128 + ((ko ^ (n & 7)) << 4));
            }
#pragma unroll
            for (int f = 0; f < 4; ++f)
#pragma unroll
                for (int g = 0; g < 4; ++g)
                    acc[f][g] = __builtin_amdgcn_mfma_f32_16x16x32_bf16(
                        __builtin_bit_cast(bf16x8_t, af[f]),
                        __builtin_bit_cast(bf16x8_t, bf[g]),
                        acc[f][g], 0, 0, 0);
        }
        __syncthreads();
    }

#pragma unroll
    for (int f = 0; f < 4; ++f) {
#pragma unroll
        for (int j = 0; j < 4; ++j) {
            const int rl = wm * 64 + f * 16 + (lane >> 4) * 4 + j;
            const bool ok = (m0 + rl) < cnt;
            const int tok = s_tok[rl];
#pragma unroll
            for (int g = 0; g < 4; ++g) {
                const int col = n0 + wn * 64 + g * 16 + (lane & 15);
                float v = acc[f][g][j] + bias[e * N_TOT + col];
                if (IS_FFN1) {
                    v = 0.5f * v * (1.0f + erff(v * 0.70710678118654752f));
                    if (ok) hout[(size_t)tok * N_TOT + col] = __float2bfloat16(v);
                } else {
                    if (ok) yout[(size_t)tok * N_TOT + col] = v;
                }
            }
        }
    }
}

extern "C" void kernel_launch(void* const* d_in, const int* in_sizes, int n_in,
                              void* d_out, int out_size, void* d_ws, size_t ws_size,
                              hipStream_t stream) {
    const float* x  = (const float*)d_in[0];
    const float* Wg = (const float*)d_in[1];
    const float* bg = (const float*)d_in[2];
    const float* W1 = (const float*)d_in[3];
    const float* b1 = (const float*)d_in[4];
    const float* W2 = (const float*)d_in[5];
    const float* b2 = (const float*)d_in[6];
    float* out = (float*)d_out;

    char* ws = (char*)d_ws;
    int* counts = (int*)(ws);
    int* bucket = (int*)(ws + WS_BUCKET_OFF);
    __hip_bfloat16* xb  = (__hip_bfloat16*)(ws + WS_XB_OFF);
    __hip_bfloat16* h   = (__hip_bfloat16*)(ws + WS_H_OFF);
    __hip_bfloat16* w1b = (__hip_bfloat16*)(ws + WS_W1B_OFF);
    __hip_bfloat16* w2b = (__hip_bfloat16*)(ws + WS_W2B_OFF);

    init_counts<<<dim3(1), dim3(64), 0, stream>>>(counts);
    router_kernel<<<dim3(N_TOK / 4), dim3(256), 0, stream>>>(x, Wg, bg, counts, bucket, xb);

    if (ws_size >= WS_NEED) {
        convert_w<D_MODEL, D_HIDDEN><<<dim3(D_HIDDEN / 64, D_MODEL / 64, N_EXP), dim3(256), 0, stream>>>(W1, w1b);
        convert_w<D_HIDDEN, D_MODEL><<<dim3(D_MODEL / 64, D_HIDDEN / 64, N_EXP), dim3(256), 0, stream>>>(W2, w2b);
        // FFN1: N=4096, K=1024, BN=128
        ffn_gemm_bf16<D_MODEL, D_HIDDEN, 128, true>
            <<<dim3((D_HIDDEN / 128) * (N_TOK / 128) * N_EXP), dim3(256), 0, stream>>>(
                xb, w1b, b1, counts, bucket, h, nullptr);
        // FFN2: N=1024, K=4096, BN=64
        ffn_gemm_bf16<D_HIDDEN, D_MODEL, 64, false>
            <<<dim3((D_MODEL / 64) * (N_TOK / 128) * N_EXP), dim3(256), 0, stream>>>(
                h, w2b, b2, counts, bucket, nullptr, out);
    } else {
        ffn_gemm_f32<D_MODEL, D_HIDDEN, true>
            <<<dim3(D_HIDDEN / 128, N_TOK / 128, N_EXP), dim3(256), 0, stream>>>(
                xb, W1, b1, counts, bucket, h, nullptr);
        ffn_gemm_f32<D_HIDDEN, D_MODEL, false>
            <<<dim3(D_MODEL / 128, N_TOK / 128, N_EXP), dim3(256), 0, stream>>>(
                h, W2, b2, counts, bucket, nullptr, out);
    }
}